// Round 1
// baseline (308.892 us; speedup 1.0000x reference)
//
#include <hip/hip_runtime.h>

// Problem: B=256, N=8192, K=16, fp32.
// out[b,n,k] = min(y[n], 0.5*(y[n-1]+y[n+1])) - param   (interior n)
//            = y[n] - param                              (n==0 or n==N-1)
// where y = x + param. Pure memory-bound 3-point stencil along N.
//
// V2: latency-bound fix. Previous version had 2 outstanding loads/thread,
// an LDS tile, and a __syncthreads whose critical path was 8 lanes doing a
// second serialized round of halo loads. Here each thread owns R_=8
// consecutive n-rows of one float4 column entirely in registers and does
// clamped redundant halo loads (rows n0-1 and n0+8; duplicates of a
// neighbor thread's loads, served by L1/L2 -> no extra HBM traffic).
// 20 independent 16B loads issued back-to-back per thread, no LDS,
// no barrier, 4096 blocks instead of 32768.

#define B_   256
#define N_   8192
#define KQ   4                          // float4 per n-row (K=16 floats)
#define R_   8                          // consecutive n-rows per thread
#define TPB  256
#define ROWS_PER_BLK ((TPB / KQ) * R_)  // 512 rows per block
#define TILES (N_ / ROWS_PER_BLK)       // 16 tiles along N

static_assert(TILES == 16, "b = blk >> 4 assumes 16 tiles");

__device__ __forceinline__ float4 f4add(float4 a, float4 b) {
    return make_float4(a.x + b.x, a.y + b.y, a.z + b.z, a.w + b.w);
}

__global__ __launch_bounds__(TPB)
void convex_kernel(const float4* __restrict__ x4,
                   const float4* __restrict__ p4,
                   float4* __restrict__ o4)
{
    const int tid = threadIdx.x;
    const int c   = tid & (KQ - 1);     // float4 column within K
    const int g   = tid >> 2;           // 0..63 row-group within block
    const int blk = blockIdx.x;
    const int t   = blk & (TILES - 1);  // tile index along N
    const int b   = blk >> 4;           // batch
    const int n0  = t * ROWS_PER_BLK + g * R_;  // first n-row of this thread

    // float4 index of (b, n0, c). Max index = 256*8192*4 = 2^23 -> int is fine.
    const int base = (b * N_ + n0) * KQ + c;

    // Halo rows n0-1 and n0+R_, clamped at the array ends (clamped values are
    // never consumed: boundary rows n==0 / n==N-1 take the y-param path).
    const int topI = (n0 > 0)        ? base - KQ       : base;
    const int botI = (n0 + R_ < N_)  ? base + R_ * KQ  : base;

    // Issue all 20 loads back-to-back: maximal MLP, no barrier.
    float4 xt = x4[topI];
    float4 pt = p4[topI];
    float4 xb = x4[botI];
    float4 pb = p4[botI];

    float4 xv[R_], pv[R_];
#pragma unroll
    for (int j = 0; j < R_; ++j) {
        xv[j] = x4[base + j * KQ];
        pv[j] = p4[base + j * KQ];
    }

    // y = x + param for rows n0-1 .. n0+R_ (halo included)
    float4 y[R_ + 2];
    y[0] = f4add(xt, pt);
#pragma unroll
    for (int j = 0; j < R_; ++j) y[j + 1] = f4add(xv[j], pv[j]);
    y[R_ + 1] = f4add(xb, pb);

#pragma unroll
    for (int j = 0; j < R_; ++j) {
        const int n = n0 + j;
        const float4 yc = y[j + 1];
        const float4 p  = pv[j];
        float4 r;
        if (n == 0 || n == N_ - 1) {
            // Dy padded to 0 at the ends -> out = y - param
            r = make_float4(yc.x - p.x, yc.y - p.y, yc.z - p.z, yc.w - p.w);
        } else {
            const float4 a = y[j];      // y[n-1]
            const float4 d = y[j + 2];  // y[n+1]
            const float4 m = make_float4(0.5f * (a.x + d.x), 0.5f * (a.y + d.y),
                                         0.5f * (a.z + d.z), 0.5f * (a.w + d.w));
            r = make_float4(fminf(yc.x, m.x) - p.x,
                            fminf(yc.y, m.y) - p.y,
                            fminf(yc.z, m.z) - p.z,
                            fminf(yc.w, m.w) - p.w);
        }
        o4[base + j * KQ] = r;
    }
}

extern "C" void kernel_launch(void* const* d_in, const int* in_sizes, int n_in,
                              void* d_out, int out_size, void* d_ws, size_t ws_size,
                              hipStream_t stream)
{
    const float4* x = (const float4*)d_in[0];
    const float4* p = (const float4*)d_in[1];
    float4*       o = (float4*)d_out;

    dim3 grid(B_ * TILES);   // 4096 blocks
    dim3 block(TPB);
    convex_kernel<<<grid, block, 0, stream>>>(x, p, o);
}